// Round 2
// baseline (1895.667 us; speedup 1.0000x reference)
//
#include <hip/hip_runtime.h>
#include <stdint.h>

typedef unsigned short u16;
typedef unsigned int   u32;
typedef unsigned long long u64;
typedef __attribute__((ext_vector_type(8))) short bf16x8;
typedef __attribute__((ext_vector_type(4))) float f32x4;

#define DEV static __device__ __forceinline__

DEV float b2f(u16 u){ u32 x = ((u32)u) << 16; float f; __builtin_memcpy(&f, &x, 4); return f; }
DEV u16 f2b(float f){ u32 x; __builtin_memcpy(&x, &f, 4); return (u16)((x + 0x7fffu + ((x >> 16) & 1u)) >> 16); }
// dual-dtype scalar load: flg=1 -> buffer is bf16, flg=0 -> buffer is fp32
DEV float ldf(const void* p, int i, int flg){
  return flg ? b2f(((const u16*)p)[i]) : ((const float*)p)[i];
}

// Problem dims: B=4, H=W=64, HW=4096, Cin=512, Cm=128, Ck=16, Cout=64
static constexpr int HW = 4096;

// ---------------------------------------------------------------------------
// Dtype detector: low 16 bits of fp32 words are mantissa bits (bf16-exponent
// plausible ~20%); of packed-bf16 words they are real bf16 values (~100%).
// flag = 1 -> buffers are bf16 ; 0 -> fp32.
// ---------------------------------------------------------------------------
__global__ void k_detect(const u32* __restrict__ x, int* __restrict__ flag)
{
  __shared__ int cnt;
  if (threadIdx.x == 0) cnt = 0;
  __syncthreads();
  const u32 w  = x[threadIdx.x];
  const u32 eb = (w >> 7) & 0xFFu;            // bf16 exponent of the LOW half
  if (eb >= 100u && eb <= 150u) atomicAdd(&cnt, 1);
  __syncthreads();
  if (threadIdx.x == 0) *flag = (cnt > 384) ? 1 : 0;
}

// ---------------------------------------------------------------------------
// Generic convert (fp32 or bf16 -> bf16), 4 elems/thread, n % 4 == 0
// ---------------------------------------------------------------------------
__global__ void k_cvt(const void* __restrict__ src, const int* __restrict__ flagp,
                      u16* __restrict__ dst, int n)
{
  const int i = (blockIdx.x * 256 + threadIdx.x) << 2;
  if (i >= n) return;
  u64 ov;
  if (*flagp){
    ov = ((const u64*)src)[i >> 2];
  } else {
    const float4 f = ((const float4*)src)[i >> 2];
    const u16 a0 = f2b(f.x), a1 = f2b(f.y), a2 = f2b(f.z), a3 = f2b(f.w);
    ov = (u64)a0 | ((u64)a1 << 16) | ((u64)a2 << 32) | ((u64)a3 << 48);
  }
  ((u64*)dst)[i >> 2] = ov;
}

// ---------------------------------------------------------------------------
// BN folding: scale = g*rsqrt(v+eps), shift = b - m*scale   (4 sets of 128)
// ---------------------------------------------------------------------------
__global__ void k_prep(
    const void* g0,const void* b0,const void* m0,const void* v0,
    const void* g1,const void* b1,const void* m1,const void* v1,
    const void* g2,const void* b2,const void* m2,const void* v2,
    const void* g3,const void* b3,const void* m3,const void* v3,
    const int* __restrict__ flagp, float* scale, float* shift)
{
  const int t = threadIdx.x;
  if (t >= 512) return;
  const int flg = *flagp;
  const int set = t >> 7, c = t & 127;
  const void *gp,*bp,*mp,*vp;
  if      (set == 0){gp=g0;bp=b0;mp=m0;vp=v0;}
  else if (set == 1){gp=g1;bp=b1;mp=m1;vp=v1;}
  else if (set == 2){gp=g2;bp=b2;mp=m2;vp=v2;}
  else              {gp=g3;bp=b3;mp=m3;vp=v3;}
  const float sc = ldf(gp,c,flg) * rsqrtf(ldf(vp,c,flg) + 1e-5f);
  scale[t] = sc;
  shift[t] = ldf(bp,c,flg) - ldf(mp,c,flg) * sc;
}

// ---------------------------------------------------------------------------
// Weight reorder+convert for 3x3 convs: [co][ci][rs] -> bf16 [co][rs][ci]
// (so a 32-wide K slice is contiguous in ci: A-frag = one 16B load)
// ---------------------------------------------------------------------------
__global__ void k_reorder_cvt(const void* __restrict__ win, const int* __restrict__ flagp,
                              u16* __restrict__ wout, int cin)
{
  const int idx = blockIdx.x * 256 + threadIdx.x;
  const int flg = *flagp;
  const int n9 = cin * 9;
  const int co = idx / n9;
  const int rem = idx - co * n9;
  const int ci = rem / 9;
  const int rs = rem - ci * 9;
  const u16 v = flg ? ((const u16*)win)[idx] : f2b(((const float*)win)[idx]);
  wout[co * n9 + rs * cin + ci] = v;
}

// ---------------------------------------------------------------------------
// Implicit-GEMM conv (MFMA 16x16x32 bf16), one wave per 16(co) x 16(px) tile.
// Weights layout: bf16 [CO][K], K = KH*KH*CIN, rs-major for KH=3 (reordered).
// EPI: 0 = BN(scale,shift)+ReLU -> bf16
//      1 = +bias -> fp32 (always, internal q buffer)
//      2 = +bias -> bf16 (always, internal v buffer)
//      3 = +bias -> flag ? bf16 : fp32 (final outputs)
// SUM2: input = x + x2 (elementwise, for the final w4 conv).
// Verified layouts: A[m=lane&15][k=quad*8+j]; B[k=quad*8+j][n=lane&15];
//                   D col=lane&15, row=quad*4+reg.
// ---------------------------------------------------------------------------
template<int CIN_, int KH_, int CO_, int EPI_, bool SUM2_>
__global__ __launch_bounds__(256) void k_conv(
    const u16* __restrict__ xin, const u16* __restrict__ xin2,
    const u16* __restrict__ wK,
    const float* __restrict__ scale, const float* __restrict__ shift,
    const void* __restrict__ bias, const int* __restrict__ flagp,
    u16* __restrict__ outB, float* __restrict__ outF)
{
  constexpr int K   = CIN_ * KH_ * KH_;
  constexpr int MT  = CO_ / 16;
  constexpr int PAD = KH_ / 2;

  const int tid  = threadIdx.x;
  const int wave = tid >> 6;
  const int lane = tid & 63;
  const int l16  = lane & 15;
  const int quad = lane >> 4;

  int tile = blockIdx.x * 4 + wave;
  const int nt = tile & 255; tile >>= 8;     // 256 pixel tiles of 16
  const int mt = tile % MT;
  const int b  = tile / MT;

  const int p  = nt * 16 + l16;              // pixel this lane supplies to B
  const int h  = p >> 6, wc = p & 63;

  const u16* wrow = wK + (size_t)(mt * 16 + l16) * K + quad * 8;
  const u16* xb   = xin + ((size_t)(b * CIN_) << 12);
  const u16* xb2  = SUM2_ ? (xin2 + ((size_t)(b * CIN_) << 12)) : nullptr;

  f32x4 acc = {0.f, 0.f, 0.f, 0.f};

  for (int r = 0; r < KH_; ++r){
    for (int s = 0; s < KH_; ++s){
      const int h2 = h + r - PAD, w2 = wc + s - PAD;
      const bool ok = ((u32)h2 < 64u) && ((u32)w2 < 64u);
      const int poff = ok ? ((h2 << 6) + w2) : 0;   // clamped: load always in-bounds
      const u16* xrs  = xb + poff;
      const u16* xrs2 = SUM2_ ? (xb2 + poff) : nullptr;
      const u16* wrs  = wrow + (r * KH_ + s) * CIN_;
      for (int ci0 = 0; ci0 < CIN_; ci0 += 32){
        bf16x8 af = *(const bf16x8*)(wrs + ci0);
        bf16x8 bfr;
        const int cib = (ci0 + quad * 8) << 12;
        #pragma unroll
        for (int j = 0; j < 8; ++j){
          u16 xv = xrs[cib + (j << 12)];
          if constexpr (SUM2_){
            const u16 x2v = xrs2[cib + (j << 12)];
            xv = f2b(b2f(xv) + b2f(x2v));
          }
          bfr[j] = ok ? (short)xv : (short)0;
        }
        acc = __builtin_amdgcn_mfma_f32_16x16x32_bf16(af, bfr, acc, 0, 0, 0);
      }
    }
  }

  int flg = 0;
  if constexpr (EPI_ != 0) flg = *flagp;

  #pragma unroll
  for (int rr = 0; rr < 4; ++rr){
    const int co = mt * 16 + quad * 4 + rr;
    float vv = acc[rr];
    const size_t addr = ((size_t)(b * CO_ + co) << 12) + p;
    if constexpr (EPI_ == 0){
      vv = fmaxf(vv * scale[co] + shift[co], 0.0f);
      outB[addr] = f2b(vv);
    } else {
      vv += ldf(bias, co, flg);
      if constexpr (EPI_ == 1)      outF[addr] = vv;
      else if constexpr (EPI_ == 2) outB[addr] = f2b(vv);
      else { if (flg) outB[addr] = f2b(vv); else outF[addr] = vv; }
    }
  }
}

// ---------------------------------------------------------------------------
// PAM pass A: row max m_i and denom l_i of softmax(S), S_ij = sum_c q[c,i]q[c,j]
// Block 512 thr = 64 i x 8 j-segments of 512. Grid = 4b x 64 i-tiles = 256.
// q is fp32 [b][16][4096].
// ---------------------------------------------------------------------------
__global__ __launch_bounds__(512) void k_pam_stats(
    const float* __restrict__ q, float* __restrict__ mrow, float* __restrict__ lrow)
{
  __shared__ float red[8][64];
  const int t  = threadIdx.x;
  const int il = t & 63, jq = t >> 6;
  const int b  = blockIdx.x >> 6;
  const int i0 = (blockIdx.x & 63) << 6;
  const int i  = i0 + il;
  const float* qb = q + (size_t)b * 16 * HW;

  float qi[16];
  #pragma unroll
  for (int c = 0; c < 16; ++c) qi[c] = qb[c * HW + i];

  const int j0 = jq * 512;
  float mx = -1e30f;
  for (int j = j0; j < j0 + 512; j += 4){
    float sx = 0.f, sy = 0.f, sz = 0.f, sw = 0.f;
    #pragma unroll
    for (int c = 0; c < 16; ++c){
      const float4 qv = *(const float4*)(qb + c * HW + j);
      sx += qi[c] * qv.x; sy += qi[c] * qv.y; sz += qi[c] * qv.z; sw += qi[c] * qv.w;
    }
    mx = fmaxf(mx, fmaxf(fmaxf(sx, sy), fmaxf(sz, sw)));
  }
  red[jq][il] = mx;
  __syncthreads();
  float m = red[0][il];
  #pragma unroll
  for (int k = 1; k < 8; ++k) m = fmaxf(m, red[k][il]);
  __syncthreads();

  float l = 0.f;
  for (int j = j0; j < j0 + 512; j += 4){
    float sx = 0.f, sy = 0.f, sz = 0.f, sw = 0.f;
    #pragma unroll
    for (int c = 0; c < 16; ++c){
      const float4 qv = *(const float4*)(qb + c * HW + j);
      sx += qi[c] * qv.x; sy += qi[c] * qv.y; sz += qi[c] * qv.z; sw += qi[c] * qv.w;
    }
    l += __expf(sx - m) + __expf(sy - m) + __expf(sz - m) + __expf(sw - m);
  }
  red[jq][il] = l;
  __syncthreads();
  if (jq == 0){
    float ls = 0.f;
    #pragma unroll
    for (int k = 0; k < 8; ++k) ls += red[k][il];
    mrow[b * HW + i] = m;
    lrow[b * HW + i] = ls;
  }
}

// ---------------------------------------------------------------------------
// PAM pass B: out[c,i] = gamma*(1/l_i)*sum_j exp(S_ij - m_i)*v[c,j] + feat1[c,i]
// Block 256 thr, i-tile 64, chunked over j (64 at a time). Grid 4b x 64 = 256.
// In-place over feat1 is safe (epilogue reads only its own element).
// ---------------------------------------------------------------------------
__global__ __launch_bounds__(256) void k_pam_out(
    const float* __restrict__ q, const u16* __restrict__ v,
    const float* __restrict__ mrow, const float* __restrict__ lrow,
    const u16* __restrict__ feat1, const void* __restrict__ gptr,
    const int* __restrict__ flagp, u16* __restrict__ out)
{
  __shared__ float vls[128 * 68];   // v chunk fp32, [c][j] stride 68
  __shared__ float pls[64 * 68];    // p chunk fp32, [i][j] stride 68

  const int t  = threadIdx.x;
  const int b  = blockIdx.x >> 6;
  const int i0 = (blockIdx.x & 63) << 6;
  const float* qb = q + (size_t)b * 16 * HW;
  const u16*   vb = v + (size_t)b * 128 * HW;

  const int ip  = t & 63, jg2 = t >> 6;   // phase-P identity
  const int il2 = t & 31, cg  = t >> 5;   // phase-V identity

  float qi[16];
  #pragma unroll
  for (int c = 0; c < 16; ++c) qi[c] = qb[c * HW + i0 + ip];
  const float mi_p = mrow[b * HW + i0 + ip];

  float acc[2][16];
  #pragma unroll
  for (int a = 0; a < 2; ++a)
    #pragma unroll
    for (int c = 0; c < 16; ++c) acc[a][c] = 0.f;

  for (int chunk = 0; chunk < 64; ++chunk){
    const int j0 = chunk << 6;
    for (int idx = t; idx < 128 * 64; idx += 256){
      const int c = idx >> 6, jj = idx & 63;
      vls[c * 68 + jj] = b2f(vb[c * HW + j0 + jj]);
    }
    #pragma unroll
    for (int j4 = 0; j4 < 4; ++j4){
      const int jj = jg2 * 16 + j4 * 4;
      float sx = 0.f, sy = 0.f, sz = 0.f, sw = 0.f;
      #pragma unroll
      for (int c = 0; c < 16; ++c){
        const float4 qv = *(const float4*)(qb + c * HW + j0 + jj);
        sx += qi[c] * qv.x; sy += qi[c] * qv.y; sz += qi[c] * qv.z; sw += qi[c] * qv.w;
      }
      float4 p4;
      p4.x = __expf(sx - mi_p); p4.y = __expf(sy - mi_p);
      p4.z = __expf(sz - mi_p); p4.w = __expf(sw - mi_p);
      *(float4*)(pls + ip * 68 + jj) = p4;
    }
    __syncthreads();
    #pragma unroll 4
    for (int jg = 0; jg < 16; ++jg){
      const int jj = jg * 4;
      const float4 p0 = *(const float4*)(pls + il2 * 68 + jj);
      const float4 p1 = *(const float4*)(pls + (il2 + 32) * 68 + jj);
      #pragma unroll
      for (int cc = 0; cc < 16; ++cc){
        const float4 vv = *(const float4*)(vls + (cg * 16 + cc) * 68 + jj);
        acc[0][cc] += p0.x * vv.x + p0.y * vv.y + p0.z * vv.z + p0.w * vv.w;
        acc[1][cc] += p1.x * vv.x + p1.y * vv.y + p1.z * vv.z + p1.w * vv.w;
      }
    }
    __syncthreads();
  }

  const float gamma = ldf(gptr, 0, *flagp);
  #pragma unroll
  for (int iw = 0; iw < 2; ++iw){
    const int i = i0 + il2 + iw * 32;
    const float linv = 1.0f / lrow[b * HW + i];
    #pragma unroll
    for (int cc = 0; cc < 16; ++cc){
      const int c = cg * 16 + cc;
      const size_t addr = (size_t)(b * 128 + c) * HW + i;
      const float o = gamma * (acc[iw][cc] * linv) + b2f(feat1[addr]);
      out[addr] = f2b(o);
    }
  }
}

// ---------------------------------------------------------------------------
// CAM attention: attn[c,d] = exp(Emin_c - E[c,d]) / sum_d exp(Emin_c - E[c,d])
// One block per (b,c): 128 threads (thread = d).
// ---------------------------------------------------------------------------
__global__ __launch_bounds__(128) void k_cam_attn(
    const u16* __restrict__ f, float* __restrict__ attn)
{
  __shared__ float fc[4096];
  __shared__ float red[128];
  const int d = threadIdx.x;
  const int c = blockIdx.x & 127, b = blockIdx.x >> 7;
  const u16* fb   = f + (size_t)b * 128 * HW;
  const u16* rowc = fb + (size_t)c * HW;
  for (int mi = d; mi < 4096; mi += 128) fc[mi] = b2f(rowc[mi]);
  __syncthreads();

  const u16* rowd = fb + (size_t)d * HW;
  float e = 0.f;
  for (int mm = 0; mm < 4096; mm += 8){
    const uint4 xv = *(const uint4*)(rowd + mm);
    const u16* px = (const u16*)&xv;
    #pragma unroll
    for (int k = 0; k < 8; ++k) e += fc[mm + k] * b2f(px[k]);
  }
  red[d] = e;
  __syncthreads();
  for (int st = 64; st > 0; st >>= 1){
    if (d < st) red[d] = fminf(red[d], red[d + st]);
    __syncthreads();
  }
  const float emin = red[0];
  __syncthreads();
  const float pd = __expf(emin - e);
  red[d] = pd;
  __syncthreads();
  for (int st = 64; st > 0; st >>= 1){
    if (d < st) red[d] += red[d + st];
    __syncthreads();
  }
  attn[(size_t)(b * 128 + c) * 128 + d] = pd / red[0];
}

// ---------------------------------------------------------------------------
// CAM output: ca_feat[c,m] = gamma * sum_d attn[c,d]*f[d,m] + f[c,m]
// Grid 4b x 128c x 8 m-chunks of 512; thread handles 2 pixels.
// ---------------------------------------------------------------------------
__global__ __launch_bounds__(256) void k_cam_out(
    const u16* __restrict__ f, const float* __restrict__ attn,
    const void* __restrict__ gptr, const int* __restrict__ flagp,
    u16* __restrict__ outb)
{
  __shared__ float arow[128];
  const int t = threadIdx.x;
  int bid = blockIdx.x;
  const int mc = bid & 7;  bid >>= 3;
  const int c  = bid & 127;
  const int b  = bid >> 7;
  if (t < 128) arow[t] = attn[(size_t)(b * 128 + c) * 128 + t];
  __syncthreads();

  const int m = mc * 512 + t * 2;
  const u16* fb = f + (size_t)b * 128 * HW;
  float a0 = 0.f, a1 = 0.f;
  for (int d = 0; d < 128; ++d){
    const u32 two = *(const u32*)(fb + (size_t)d * HW + m);
    const float ad = arow[d];
    a0 += ad * b2f((u16)(two & 0xffffu));
    a1 += ad * b2f((u16)(two >> 16));
  }
  const float g = ldf(gptr, 0, *flagp);
  const size_t addr = (size_t)(b * 128 + c) * HW + m;
  outb[addr]     = f2b(g * a0 + b2f(f[addr]));
  outb[addr + 1] = f2b(g * a1 + b2f(f[addr + 1]));
}

// ---------------------------------------------------------------------------
extern "C" void kernel_launch(void* const* d_in, const int* in_sizes, int n_in,
                              void* d_out, int out_size, void* d_ws, size_t ws_size,
                              hipStream_t stream)
{
  (void)in_sizes; (void)n_in; (void)out_size; (void)ws_size;

  const void* x    = d_in[0];
  const void* w11  = d_in[1];
  const void* g11  = d_in[2];
  const void* b11  = d_in[3];
  const void* m11  = d_in[4];
  const void* v11  = d_in[5];
  const void* w12  = d_in[6];
  const void* g12  = d_in[7];
  const void* b12  = d_in[8];
  const void* m12  = d_in[9];
  const void* v12  = d_in[10];
  const void* kw   = d_in[11];
  const void* kb   = d_in[12];
  const void* vw   = d_in[13];
  const void* vb   = d_in[14];
  const void* pgam = d_in[15];
  const void* cgam = d_in[16];
  const void* w21  = d_in[17];
  const void* g21  = d_in[18];
  const void* b21  = d_in[19];
  const void* m21  = d_in[20];
  const void* v21  = d_in[21];
  const void* w22  = d_in[22];
  const void* g22  = d_in[23];
  const void* b22  = d_in[24];
  const void* m22  = d_in[25];
  const void* v22  = d_in[26];
  const void* w31  = d_in[27];
  const void* b31  = d_in[28];
  const void* w32  = d_in[29];
  const void* b32  = d_in[30];
  const void* w4   = d_in[31];
  const void* b4   = d_in[32];

  char* wsb = (char*)d_ws;
  size_t off = 0;
  auto alloc = [&](size_t bytes) -> void* {
    void* pp = wsb + off;
    off += (bytes + 255) & ~(size_t)255;
    return pp;
  };
  const size_t FEAT = (size_t)4 * 128 * HW;     // 2,097,152 elems
  u16*   xbf    = (u16*)alloc((size_t)4 * 512 * HW * 2);   // canonical bf16 x
  u16*   feat1  = (u16*)alloc(FEAT * 2);        // later: pa_feat (in-place)
  u16*   feat2  = (u16*)alloc(FEAT * 2);
  u16*   cafeat = (u16*)alloc(FEAT * 2);
  u16*   vbuf   = (u16*)alloc(FEAT * 2);        // later: pa_conv
  u16*   caconv = (u16*)alloc(FEAT * 2);
  float* q      = (float*)alloc((size_t)4 * 16 * HW * 4);
  float* mrow   = (float*)alloc((size_t)4 * HW * 4);
  float* lrow   = (float*)alloc((size_t)4 * HW * 4);
  float* attn   = (float*)alloc((size_t)4 * 128 * 128 * 4);
  float* scale  = (float*)alloc(512 * 4);
  float* shift  = (float*)alloc(512 * 4);
  u16*   w11r   = (u16*)alloc((size_t)128 * 4608 * 2);
  u16*   w12r   = (u16*)alloc((size_t)128 * 4608 * 2);
  u16*   w21r   = (u16*)alloc((size_t)128 * 1152 * 2);
  u16*   w22r   = (u16*)alloc((size_t)128 * 1152 * 2);
  u16*   kwb    = (u16*)alloc((size_t)16 * 128 * 2);
  u16*   vwb    = (u16*)alloc((size_t)128 * 128 * 2);
  u16*   w31b   = (u16*)alloc((size_t)64 * 128 * 2);
  u16*   w32b   = (u16*)alloc((size_t)64 * 128 * 2);
  u16*   w4b    = (u16*)alloc((size_t)64 * 128 * 2);
  int*   flag   = (int*)alloc(256);

  // dtype detection + canonicalization
  k_detect<<<1, 512, 0, stream>>>((const u32*)x, flag);
  k_prep<<<1, 512, 0, stream>>>(g11,b11,m11,v11, g12,b12,m12,v12,
                                g21,b21,m21,v21, g22,b22,m22,v22, flag, scale, shift);
  k_cvt<<<8192, 256, 0, stream>>>(x, flag, xbf, 4 * 512 * HW);
  k_reorder_cvt<<<2304, 256, 0, stream>>>(w11, flag, w11r, 512);
  k_reorder_cvt<<<2304, 256, 0, stream>>>(w12, flag, w12r, 512);
  k_reorder_cvt<<<576, 256, 0, stream>>>(w21, flag, w21r, 128);
  k_reorder_cvt<<<576, 256, 0, stream>>>(w22, flag, w22r, 128);
  k_cvt<<<2, 256, 0, stream>>>(kw, flag, kwb, 16 * 128);
  k_cvt<<<16, 256, 0, stream>>>(vw, flag, vwb, 128 * 128);
  k_cvt<<<8, 256, 0, stream>>>(w31, flag, w31b, 64 * 128);
  k_cvt<<<8, 256, 0, stream>>>(w32, flag, w32b, 64 * 128);
  k_cvt<<<8, 256, 0, stream>>>(w4, flag, w4b, 64 * 128);

  // trunk convs
  k_conv<512,3,128,0,false><<<2048,256,0,stream>>>(xbf, nullptr, w11r, scale,       shift,       nullptr, flag, feat1, nullptr);
  k_conv<512,3,128,0,false><<<2048,256,0,stream>>>(xbf, nullptr, w12r, scale + 128, shift + 128, nullptr, flag, feat2, nullptr);

  // PAM
  k_conv<128,1,16,1,false><<<256,256,0,stream>>>(feat1, nullptr, kwb, nullptr, nullptr, kb, flag, nullptr, q);
  k_conv<128,1,128,2,false><<<2048,256,0,stream>>>(feat1, nullptr, vwb, nullptr, nullptr, vb, flag, vbuf, nullptr);
  k_pam_stats<<<256, 512, 0, stream>>>(q, mrow, lrow);
  k_pam_out<<<256, 256, 0, stream>>>(q, vbuf, mrow, lrow, feat1, pgam, flag, feat1);  // feat1 -> pa_feat in-place

  // CAM
  k_cam_attn<<<512, 128, 0, stream>>>(feat2, attn);
  k_cam_out<<<4096, 256, 0, stream>>>(feat2, attn, cgam, flag, cafeat);

  // second convs
  k_conv<128,3,128,0,false><<<2048,256,0,stream>>>(feat1,  nullptr, w21r, scale + 256, shift + 256, nullptr, flag, vbuf,   nullptr); // pa_conv
  k_conv<128,3,128,0,false><<<2048,256,0,stream>>>(cafeat, nullptr, w22r, scale + 384, shift + 384, nullptr, flag, caconv, nullptr); // ca_conv

  // heads -> d_out [3][4][64][4096] (dtype per flag)
  const size_t SEC = (size_t)4 * 64 * HW;  // 1,048,576 elements per section
  u16*   outB = (u16*)d_out;
  float* outF = (float*)d_out;
  k_conv<128,1,64,3,false><<<1024,256,0,stream>>>(vbuf,   nullptr, w31b, nullptr, nullptr, b31, flag, outB,           outF);
  k_conv<128,1,64,3,false><<<1024,256,0,stream>>>(caconv, nullptr, w32b, nullptr, nullptr, b32, flag, outB + SEC,     outF + SEC);
  k_conv<128,1,64,3,true ><<<1024,256,0,stream>>>(vbuf,   caconv,  w4b,  nullptr, nullptr, b4,  flag, outB + 2 * SEC, outF + 2 * SEC);
}

// Round 3
// 973.572 us; speedup vs baseline: 1.9471x; 1.9471x over previous
//
#include <hip/hip_runtime.h>
#include <stdint.h>

typedef unsigned short u16;
typedef unsigned int   u32;
typedef unsigned long long u64;
typedef __attribute__((ext_vector_type(8))) short bf16x8;
typedef __attribute__((ext_vector_type(4))) float f32x4;

#define DEV static __device__ __forceinline__

DEV float b2f(u16 u){ u32 x = ((u32)u) << 16; float f; __builtin_memcpy(&f, &x, 4); return f; }
DEV u16 f2b(float f){ u32 x; __builtin_memcpy(&x, &f, 4); return (u16)((x + 0x7fffu + ((x >> 16) & 1u)) >> 16); }
// dual-dtype scalar load: flg=1 -> buffer is bf16, flg=0 -> buffer is fp32
DEV float ldf(const void* p, int i, int flg){
  return flg ? b2f(((const u16*)p)[i]) : ((const float*)p)[i];
}

// Problem dims: B=4, H=W=64, HW=4096, Cin=512, Cm=128, Ck=16, Cout=64
static constexpr int HW = 4096;

// ---------------------------------------------------------------------------
// Dtype detector: low 16 bits of fp32 words are mantissa bits (bf16-exponent
// plausible ~20%); of packed-bf16 words they are real bf16 values (~100%).
// flag = 1 -> buffers are bf16 ; 0 -> fp32.
// ---------------------------------------------------------------------------
__global__ void k_detect(const u32* __restrict__ x, int* __restrict__ flag)
{
  __shared__ int cnt;
  if (threadIdx.x == 0) cnt = 0;
  __syncthreads();
  const u32 w  = x[threadIdx.x];
  const u32 eb = (w >> 7) & 0xFFu;            // bf16 exponent of the LOW half
  if (eb >= 100u && eb <= 150u) atomicAdd(&cnt, 1);
  __syncthreads();
  if (threadIdx.x == 0) *flag = (cnt > 384) ? 1 : 0;
}

// ---------------------------------------------------------------------------
// Generic convert (fp32 or bf16 -> bf16), 4 elems/thread, n % 4 == 0
// ---------------------------------------------------------------------------
__global__ void k_cvt(const void* __restrict__ src, const int* __restrict__ flagp,
                      u16* __restrict__ dst, int n)
{
  const int i = (blockIdx.x * 256 + threadIdx.x) << 2;
  if (i >= n) return;
  u64 ov;
  if (*flagp){
    ov = ((const u64*)src)[i >> 2];
  } else {
    const float4 f = ((const float4*)src)[i >> 2];
    const u16 a0 = f2b(f.x), a1 = f2b(f.y), a2 = f2b(f.z), a3 = f2b(f.w);
    ov = (u64)a0 | ((u64)a1 << 16) | ((u64)a2 << 32) | ((u64)a3 << 48);
  }
  ((u64*)dst)[i >> 2] = ov;
}

// ---------------------------------------------------------------------------
// BN folding: scale = g*rsqrt(v+eps), shift = b - m*scale   (4 sets of 128)
// ---------------------------------------------------------------------------
__global__ void k_prep(
    const void* g0,const void* b0,const void* m0,const void* v0,
    const void* g1,const void* b1,const void* m1,const void* v1,
    const void* g2,const void* b2,const void* m2,const void* v2,
    const void* g3,const void* b3,const void* m3,const void* v3,
    const int* __restrict__ flagp, float* scale, float* shift)
{
  const int t = threadIdx.x;
  if (t >= 512) return;
  const int flg = *flagp;
  const int set = t >> 7, c = t & 127;
  const void *gp,*bp,*mp,*vp;
  if      (set == 0){gp=g0;bp=b0;mp=m0;vp=v0;}
  else if (set == 1){gp=g1;bp=b1;mp=m1;vp=v1;}
  else if (set == 2){gp=g2;bp=b2;mp=m2;vp=v2;}
  else              {gp=g3;bp=b3;mp=m3;vp=v3;}
  const float sc = ldf(gp,c,flg) * rsqrtf(ldf(vp,c,flg) + 1e-5f);
  scale[t] = sc;
  shift[t] = ldf(bp,c,flg) - ldf(mp,c,flg) * sc;
}

// ---------------------------------------------------------------------------
// Weight reorder+convert for 3x3 convs: [co][ci][rs] -> bf16 [co][rs][ci]
// ---------------------------------------------------------------------------
__global__ void k_reorder_cvt(const void* __restrict__ win, const int* __restrict__ flagp,
                              u16* __restrict__ wout, int cin)
{
  const int idx = blockIdx.x * 256 + threadIdx.x;
  const int flg = *flagp;
  const int n9 = cin * 9;
  const int co = idx / n9;
  const int rem = idx - co * n9;
  const int ci = rem / 9;
  const int rs = rem - ci * 9;
  const u16 v = flg ? ((const u16*)win)[idx] : f2b(((const float*)win)[idx]);
  wout[co * n9 + rs * cin + ci] = v;
}

// ---------------------------------------------------------------------------
// Implicit-GEMM conv (MFMA 16x16x32 bf16), one wave per 16(co) x 16(px) tile.
// EPI: 0 = BN(scale,shift)+ReLU -> bf16
//      2 = +bias -> bf16
//      3 = +bias -> flag ? bf16 : fp32 (final outputs)
//      4 = +bias -> qT hi/lo bf16 pair, layout [b][pixel][16] (PAM q)
// SUM2: input = x + x2 (elementwise, for the final w4 conv).
// Verified layouts: A[m=lane&15][k=quad*8+j]; B[k=quad*8+j][n=lane&15];
//                   D col=lane&15, row=quad*4+reg.
// ---------------------------------------------------------------------------
template<int CIN_, int KH_, int CO_, int EPI_, bool SUM2_>
__global__ __launch_bounds__(256) void k_conv(
    const u16* __restrict__ xin, const u16* __restrict__ xin2,
    const u16* __restrict__ wK,
    const float* __restrict__ scale, const float* __restrict__ shift,
    const void* __restrict__ bias, const int* __restrict__ flagp,
    u16* __restrict__ outB, float* __restrict__ outF)
{
  constexpr int K   = CIN_ * KH_ * KH_;
  constexpr int MT  = CO_ / 16;
  constexpr int PAD = KH_ / 2;

  const int tid  = threadIdx.x;
  const int wave = tid >> 6;
  const int lane = tid & 63;
  const int l16  = lane & 15;
  const int quad = lane >> 4;

  int tile = blockIdx.x * 4 + wave;
  const int nt = tile & 255; tile >>= 8;     // 256 pixel tiles of 16
  const int mt = tile % MT;
  const int b  = tile / MT;

  const int p  = nt * 16 + l16;              // pixel this lane supplies to B
  const int h  = p >> 6, wc = p & 63;

  const u16* wrow = wK + (size_t)(mt * 16 + l16) * K + quad * 8;
  const u16* xb   = xin + ((size_t)(b * CIN_) << 12);
  const u16* xb2  = SUM2_ ? (xin2 + ((size_t)(b * CIN_) << 12)) : nullptr;

  f32x4 acc = {0.f, 0.f, 0.f, 0.f};

  for (int r = 0; r < KH_; ++r){
    for (int s = 0; s < KH_; ++s){
      const int h2 = h + r - PAD, w2 = wc + s - PAD;
      const bool ok = ((u32)h2 < 64u) && ((u32)w2 < 64u);
      const int poff = ok ? ((h2 << 6) + w2) : 0;   // clamped: load always in-bounds
      const u16* xrs  = xb + poff;
      const u16* xrs2 = SUM2_ ? (xb2 + poff) : nullptr;
      const u16* wrs  = wrow + (r * KH_ + s) * CIN_;
      for (int ci0 = 0; ci0 < CIN_; ci0 += 32){
        bf16x8 af = *(const bf16x8*)(wrs + ci0);
        bf16x8 bfr;
        const int cib = (ci0 + quad * 8) << 12;
        #pragma unroll
        for (int j = 0; j < 8; ++j){
          u16 xv = xrs[cib + (j << 12)];
          if constexpr (SUM2_){
            const u16 x2v = xrs2[cib + (j << 12)];
            xv = f2b(b2f(xv) + b2f(x2v));
          }
          bfr[j] = ok ? (short)xv : (short)0;
        }
        acc = __builtin_amdgcn_mfma_f32_16x16x32_bf16(af, bfr, acc, 0, 0, 0);
      }
    }
  }

  int flg = 0;
  if constexpr (EPI_ != 0) flg = *flagp;

  #pragma unroll
  for (int rr = 0; rr < 4; ++rr){
    const int co = mt * 16 + quad * 4 + rr;
    float vv = acc[rr];
    const size_t addr = ((size_t)(b * CO_ + co) << 12) + p;
    if constexpr (EPI_ == 0){
      vv = fmaxf(vv * scale[co] + shift[co], 0.0f);
      outB[addr] = f2b(vv);
    } else if constexpr (EPI_ == 4){
      vv += ldf(bias, co, flg);
      const u16 hb = f2b(vv);
      const float lo = vv - b2f(hb);
      const size_t qaddr = ((size_t)b * 4096 + p) * 16 + co;
      outB[qaddr] = hb;
      ((u16*)outF)[qaddr] = f2b(lo);
    } else {
      vv += ldf(bias, co, flg);
      if constexpr (EPI_ == 2) outB[addr] = f2b(vv);
      else { if (flg) outB[addr] = f2b(vv); else outF[addr] = vv; }
    }
  }
}

// ---------------------------------------------------------------------------
// PAM flash attention (online softmax), MFMA everywhere.
// Grid 1024 = b(4) x i-tile(64, TI=64) x j-segment(4, 1024 j each).
// Block 256 thr = 4 waves; wave w owns i rows [i0+w*16, i0+w*16+16).
// qT hi/lo: [b][4096 px][16 c] bf16. v: [b][128 c][4096 px] bf16.
// Emits partial O (bf16, [bid][64 i][128 c]) + m,l (fp32) for k_pam_comb.
// ---------------------------------------------------------------------------
__global__ __launch_bounds__(256) void k_pam_flash(
    const u16* __restrict__ qTh, const u16* __restrict__ qTl,
    const u16* __restrict__ v,
    u16* __restrict__ po, float* __restrict__ pm, float* __restrict__ pl)
{
  __shared__ u16 vls[128 * 72];   // v chunk [c][j], stride 72 (144B rows, 16B-aligned)
  __shared__ u16 pls[64 * 72];    // p chunk [i][j]

  const int t    = threadIdx.x;
  const int wave = t >> 6, lane = t & 63;
  const int l16  = lane & 15, quad = lane >> 4;

  const int bid = blockIdx.x;
  const int js  = bid & 3, it = (bid >> 2) & 63, b = bid >> 8;
  const int i0  = it * 64;
  const int jbase = js * 1024;

  const u16* qTbh = qTh + ((size_t)b * 4096) * 16;
  const u16* qTbl = qTl + ((size_t)b * 4096) * 16;
  const u16* vb   = v + ((size_t)b * 128) * 4096;

  // A-frags (i side, K=c zero-padded 16->32: quads 2,3 zero), loaded once
  bf16x8 afh = {}, afl = {};
  {
    const int i = i0 + wave * 16 + l16;
    if (quad < 2){
      *(uint4*)&afh = *(const uint4*)(qTbh + (size_t)i * 16 + quad * 8);
      *(uint4*)&afl = *(const uint4*)(qTbl + (size_t)i * 16 + quad * 8);
    }
  }

  f32x4 oacc[8];
  #pragma unroll
  for (int cs = 0; cs < 8; ++cs){ oacc[cs][0]=0.f; oacc[cs][1]=0.f; oacc[cs][2]=0.f; oacc[cs][3]=0.f; }
  float m_run[4], l_run[4];
  #pragma unroll
  for (int r = 0; r < 4; ++r){ m_run[r] = -1e30f; l_run[r] = 0.f; }

  const int vc = t >> 1, vjh = (t & 1) * 32;   // v staging identity

  for (int ch = 0; ch < 16; ++ch){
    const int j0 = jbase + ch * 64;
    __syncthreads();   // prev chunk's vls reads complete
    // stage v chunk [128 c][64 j]
    {
      const u16* src = vb + (size_t)vc * 4096 + j0 + vjh;
      u16* dst = vls + vc * 72 + vjh;
      *(uint4*)(dst)      = *(const uint4*)(src);
      *(uint4*)(dst + 8)  = *(const uint4*)(src + 8);
      *(uint4*)(dst + 16) = *(const uint4*)(src + 16);
      *(uint4*)(dst + 24) = *(const uint4*)(src + 24);
    }
    // QK^T: S[i][j] = sum_c q[i][c] q[j][c], hi/lo split for ~fp32 accuracy
    f32x4 sacc[4];
    #pragma unroll
    for (int ns = 0; ns < 4; ++ns){
      bf16x8 bh = {}, bl = {};
      const int j = j0 + ns * 16 + l16;
      if (quad < 2){
        *(uint4*)&bh = *(const uint4*)(qTbh + (size_t)j * 16 + quad * 8);
        *(uint4*)&bl = *(const uint4*)(qTbl + (size_t)j * 16 + quad * 8);
      }
      f32x4 z = {0.f, 0.f, 0.f, 0.f};
      z = __builtin_amdgcn_mfma_f32_16x16x32_bf16(afh, bh, z, 0, 0, 0);
      z = __builtin_amdgcn_mfma_f32_16x16x32_bf16(afh, bl, z, 0, 0, 0);
      z = __builtin_amdgcn_mfma_f32_16x16x32_bf16(afl, bh, z, 0, 0, 0);
      sacc[ns] = z;
    }
    // online softmax per row (row = quad*4+r, replicated over 16 lanes)
    float pv[4][4];  // [ns][r]
    #pragma unroll
    for (int r = 0; r < 4; ++r){
      float mx = fmaxf(fmaxf(sacc[0][r], sacc[1][r]), fmaxf(sacc[2][r], sacc[3][r]));
      mx = fmaxf(mx, __shfl_xor(mx, 1));
      mx = fmaxf(mx, __shfl_xor(mx, 2));
      mx = fmaxf(mx, __shfl_xor(mx, 4));
      mx = fmaxf(mx, __shfl_xor(mx, 8));
      const float mnew  = fmaxf(m_run[r], mx);
      const float alpha = __expf(m_run[r] - mnew);
      m_run[r] = mnew;
      float rs = 0.f;
      #pragma unroll
      for (int ns = 0; ns < 4; ++ns){
        pv[ns][r] = __expf(sacc[ns][r] - mnew);
        rs += pv[ns][r];
      }
      rs += __shfl_xor(rs, 1); rs += __shfl_xor(rs, 2);
      rs += __shfl_xor(rs, 4); rs += __shfl_xor(rs, 8);
      l_run[r] = l_run[r] * alpha + rs;
      #pragma unroll
      for (int cs = 0; cs < 8; ++cs) oacc[cs][r] *= alpha;
    }
    // P -> LDS (C-layout -> A-layout round-trip); wave-private rows
    #pragma unroll
    for (int r = 0; r < 4; ++r)
      #pragma unroll
      for (int ns = 0; ns < 4; ++ns)
        pls[(wave * 16 + quad * 4 + r) * 72 + ns * 16 + l16] = f2b(pv[ns][r]);
    __syncthreads();   // vls staged (pls same-wave ordering via lgkmcnt)
    // PV: O[i][c] += sum_j P[i][j] V[c][j]
    #pragma unroll
    for (int ks = 0; ks < 2; ++ks){
      bf16x8 pf = *(const bf16x8*)(pls + (wave * 16 + l16) * 72 + ks * 32 + quad * 8);
      #pragma unroll
      for (int cs = 0; cs < 8; ++cs){
        bf16x8 vf = *(const bf16x8*)(vls + (cs * 16 + l16) * 72 + ks * 32 + quad * 8);
        oacc[cs] = __builtin_amdgcn_mfma_f32_16x16x32_bf16(pf, vf, oacc[cs], 0, 0, 0);
      }
    }
  }

  // partials out
  u16* pob = po + (size_t)bid * 64 * 128;
  #pragma unroll
  for (int cs = 0; cs < 8; ++cs)
    #pragma unroll
    for (int r = 0; r < 4; ++r)
      pob[(wave * 16 + quad * 4 + r) * 128 + cs * 16 + l16] = f2b(oacc[cs][r]);
  if (l16 == 0){
    #pragma unroll
    for (int r = 0; r < 4; ++r){
      pm[(size_t)bid * 64 + wave * 16 + quad * 4 + r] = m_run[r];
      pl[(size_t)bid * 64 + wave * 16 + quad * 4 + r] = l_run[r];
    }
  }
}

// ---------------------------------------------------------------------------
// PAM combine: merge 4 j-segment partials, apply gamma + residual, transpose
// [i][c] -> [c][i] via LDS. Grid 256 = b(4) x i-tile(64). In-place over feat1.
// ---------------------------------------------------------------------------
__global__ __launch_bounds__(256) void k_pam_comb(
    const u16* __restrict__ po, const float* __restrict__ pm, const float* __restrict__ pl,
    const u16* __restrict__ feat1, const void* __restrict__ gptr,
    const int* __restrict__ flagp, u16* __restrict__ out)
{
  __shared__ float wgt[4][64];
  __shared__ float ols[128][65];
  const int t  = threadIdx.x;
  const int it = blockIdx.x & 63, b = blockIdx.x >> 6;
  const int base = (b * 64 + it) * 4;
  if (t < 64){
    const float m0 = pm[(size_t)(base+0)*64 + t];
    const float m1 = pm[(size_t)(base+1)*64 + t];
    const float m2 = pm[(size_t)(base+2)*64 + t];
    const float m3 = pm[(size_t)(base+3)*64 + t];
    const float M  = fmaxf(fmaxf(m0, m1), fmaxf(m2, m3));
    const float e0 = __expf(m0 - M), e1 = __expf(m1 - M);
    const float e2 = __expf(m2 - M), e3 = __expf(m3 - M);
    const float L  = pl[(size_t)(base+0)*64+t]*e0 + pl[(size_t)(base+1)*64+t]*e1
                   + pl[(size_t)(base+2)*64+t]*e2 + pl[(size_t)(base+3)*64+t]*e3;
    const float li = 1.0f / L;
    wgt[0][t] = e0*li; wgt[1][t] = e1*li; wgt[2][t] = e2*li; wgt[3][t] = e3*li;
  }
  __syncthreads();
  const int c = t & 127, ih = t >> 7;
  for (int st = 0; st < 32; ++st){
    const int il = ih + st * 2;
    float acc = 0.f;
    #pragma unroll
    for (int s = 0; s < 4; ++s)
      acc += wgt[s][il] * b2f(po[((size_t)(base+s)*64 + il)*128 + c]);
    ols[c][il] = acc;
  }
  __syncthreads();
  const float g = ldf(gptr, 0, *flagp);
  const int il2 = t & 63, ch = t >> 6;
  const int i0 = it * 64;
  for (int st = 0; st < 32; ++st){
    const int cc = ch + st * 4;
    const size_t addr = ((size_t)(b * 128) + cc) * 4096 + i0 + il2;
    out[addr] = f2b(g * ols[cc][il2] + b2f(feat1[addr]));
  }
}

// ---------------------------------------------------------------------------
// CAM attention: attn[c,d] = exp(Emin_c - E[c,d]) / sum_d exp(Emin_c - E[c,d])
// One block per (b,c): 128 threads (thread = d).
// ---------------------------------------------------------------------------
__global__ __launch_bounds__(128) void k_cam_attn(
    const u16* __restrict__ f, float* __restrict__ attn)
{
  __shared__ float fc[4096];
  __shared__ float red[128];
  const int d = threadIdx.x;
  const int c = blockIdx.x & 127, b = blockIdx.x >> 7;
  const u16* fb   = f + (size_t)b * 128 * HW;
  const u16* rowc = fb + (size_t)c * HW;
  for (int mi = d; mi < 4096; mi += 128) fc[mi] = b2f(rowc[mi]);
  __syncthreads();

  const u16* rowd = fb + (size_t)d * HW;
  float e = 0.f;
  for (int mm = 0; mm < 4096; mm += 8){
    const uint4 xv = *(const uint4*)(rowd + mm);
    const u16* px = (const u16*)&xv;
    #pragma unroll
    for (int k = 0; k < 8; ++k) e += fc[mm + k] * b2f(px[k]);
  }
  red[d] = e;
  __syncthreads();
  for (int st = 64; st > 0; st >>= 1){
    if (d < st) red[d] = fminf(red[d], red[d + st]);
    __syncthreads();
  }
  const float emin = red[0];
  __syncthreads();
  const float pd = __expf(emin - e);
  red[d] = pd;
  __syncthreads();
  for (int st = 64; st > 0; st >>= 1){
    if (d < st) red[d] += red[d + st];
    __syncthreads();
  }
  attn[(size_t)(b * 128 + c) * 128 + d] = pd / red[0];
}

// ---------------------------------------------------------------------------
// CAM output: ca_feat[c,m] = gamma * sum_d attn[c,d]*f[d,m] + f[c,m]
// Grid 4b x 128c x 8 m-chunks of 512; thread handles 2 pixels.
// ---------------------------------------------------------------------------
__global__ __launch_bounds__(256) void k_cam_out(
    const u16* __restrict__ f, const float* __restrict__ attn,
    const void* __restrict__ gptr, const int* __restrict__ flagp,
    u16* __restrict__ outb)
{
  __shared__ float arow[128];
  const int t = threadIdx.x;
  int bid = blockIdx.x;
  const int mc = bid & 7;  bid >>= 3;
  const int c  = bid & 127;
  const int b  = bid >> 7;
  if (t < 128) arow[t] = attn[(size_t)(b * 128 + c) * 128 + t];
  __syncthreads();

  const int m = mc * 512 + t * 2;
  const u16* fb = f + (size_t)b * 128 * HW;
  float a0 = 0.f, a1 = 0.f;
  for (int d = 0; d < 128; ++d){
    const u32 two = *(const u32*)(fb + (size_t)d * HW + m);
    const float ad = arow[d];
    a0 += ad * b2f((u16)(two & 0xffffu));
    a1 += ad * b2f((u16)(two >> 16));
  }
  const float g = ldf(gptr, 0, *flagp);
  const size_t addr = (size_t)(b * 128 + c) * HW + m;
  outb[addr]     = f2b(g * a0 + b2f(f[addr]));
  outb[addr + 1] = f2b(g * a1 + b2f(f[addr + 1]));
}

// ---------------------------------------------------------------------------
extern "C" void kernel_launch(void* const* d_in, const int* in_sizes, int n_in,
                              void* d_out, int out_size, void* d_ws, size_t ws_size,
                              hipStream_t stream)
{
  (void)in_sizes; (void)n_in; (void)out_size; (void)ws_size;

  const void* x    = d_in[0];
  const void* w11  = d_in[1];
  const void* g11  = d_in[2];
  const void* b11  = d_in[3];
  const void* m11  = d_in[4];
  const void* v11  = d_in[5];
  const void* w12  = d_in[6];
  const void* g12  = d_in[7];
  const void* b12  = d_in[8];
  const void* m12  = d_in[9];
  const void* v12  = d_in[10];
  const void* kw   = d_in[11];
  const void* kb   = d_in[12];
  const void* vw   = d_in[13];
  const void* vb   = d_in[14];
  const void* pgam = d_in[15];
  const void* cgam = d_in[16];
  const void* w21  = d_in[17];
  const void* g21  = d_in[18];
  const void* b21  = d_in[19];
  const void* m21  = d_in[20];
  const void* v21  = d_in[21];
  const void* w22  = d_in[22];
  const void* g22  = d_in[23];
  const void* b22  = d_in[24];
  const void* m22  = d_in[25];
  const void* v22  = d_in[26];
  const void* w31  = d_in[27];
  const void* b31  = d_in[28];
  const void* w32  = d_in[29];
  const void* b32  = d_in[30];
  const void* w4   = d_in[31];
  const void* b4   = d_in[32];

  char* wsb = (char*)d_ws;
  size_t off = 0;
  auto alloc = [&](size_t bytes) -> void* {
    void* pp = wsb + off;
    off += (bytes + 255) & ~(size_t)255;
    return pp;
  };
  const size_t FEAT = (size_t)4 * 128 * HW;     // 2,097,152 elems
  u16*   xbf    = (u16*)alloc((size_t)4 * 512 * HW * 2);   // canonical bf16 x; DEAD after
                                                           // trunk convs -> reused as po
  u16*   feat1  = (u16*)alloc(FEAT * 2);        // later: pa_feat (in-place)
  u16*   feat2  = (u16*)alloc(FEAT * 2);
  u16*   cafeat = (u16*)alloc(FEAT * 2);
  u16*   vbuf   = (u16*)alloc(FEAT * 2);        // later: pa_conv
  u16*   caconv = (u16*)alloc(FEAT * 2);
  u16*   qTh    = (u16*)alloc((size_t)4 * HW * 16 * 2);
  u16*   qTl    = (u16*)alloc((size_t)4 * HW * 16 * 2);
  float* pm     = (float*)alloc((size_t)1024 * 64 * 4);
  float* pl     = (float*)alloc((size_t)1024 * 64 * 4);
  float* attn   = (float*)alloc((size_t)4 * 128 * 128 * 4);
  float* scale  = (float*)alloc(512 * 4);
  float* shift  = (float*)alloc(512 * 4);
  u16*   w11r   = (u16*)alloc((size_t)128 * 4608 * 2);
  u16*   w12r   = (u16*)alloc((size_t)128 * 4608 * 2);
  u16*   w21r   = (u16*)alloc((size_t)128 * 1152 * 2);
  u16*   w22r   = (u16*)alloc((size_t)128 * 1152 * 2);
  u16*   kwb    = (u16*)alloc((size_t)16 * 128 * 2);
  u16*   vwb    = (u16*)alloc((size_t)128 * 128 * 2);
  u16*   w31b   = (u16*)alloc((size_t)64 * 128 * 2);
  u16*   w32b   = (u16*)alloc((size_t)64 * 128 * 2);
  u16*   w4b    = (u16*)alloc((size_t)64 * 128 * 2);
  int*   flag   = (int*)alloc(256);
  u16*   po     = xbf;  // 1024*64*128*2 = 16 MB, exactly xbf's footprint; xbf dead by then

  // dtype detection + canonicalization
  k_detect<<<1, 512, 0, stream>>>((const u32*)x, flag);
  k_prep<<<1, 512, 0, stream>>>(g11,b11,m11,v11, g12,b12,m12,v12,
                                g21,b21,m21,v21, g22,b22,m22,v22, flag, scale, shift);
  k_cvt<<<8192, 256, 0, stream>>>(x, flag, xbf, 4 * 512 * HW);
  k_reorder_cvt<<<2304, 256, 0, stream>>>(w11, flag, w11r, 512);
  k_reorder_cvt<<<2304, 256, 0, stream>>>(w12, flag, w12r, 512);
  k_reorder_cvt<<<576, 256, 0, stream>>>(w21, flag, w21r, 128);
  k_reorder_cvt<<<576, 256, 0, stream>>>(w22, flag, w22r, 128);
  k_cvt<<<2, 256, 0, stream>>>(kw, flag, kwb, 16 * 128);
  k_cvt<<<16, 256, 0, stream>>>(vw, flag, vwb, 128 * 128);
  k_cvt<<<8, 256, 0, stream>>>(w31, flag, w31b, 64 * 128);
  k_cvt<<<8, 256, 0, stream>>>(w32, flag, w32b, 64 * 128);
  k_cvt<<<8, 256, 0, stream>>>(w4, flag, w4b, 64 * 128);

  // trunk convs (last readers of xbf)
  k_conv<512,3,128,0,false><<<2048,256,0,stream>>>(xbf, nullptr, w11r, scale,       shift,       nullptr, flag, feat1, nullptr);
  k_conv<512,3,128,0,false><<<2048,256,0,stream>>>(xbf, nullptr, w12r, scale + 128, shift + 128, nullptr, flag, feat2, nullptr);

  // PAM
  k_conv<128,1,16,4,false><<<256,256,0,stream>>>(feat1, nullptr, kwb, nullptr, nullptr, kb, flag, qTh, (float*)qTl);
  k_conv<128,1,128,2,false><<<2048,256,0,stream>>>(feat1, nullptr, vwb, nullptr, nullptr, vb, flag, vbuf, nullptr);
  k_pam_flash<<<1024, 256, 0, stream>>>(qTh, qTl, vbuf, po, pm, pl);
  k_pam_comb<<<256, 256, 0, stream>>>(po, pm, pl, feat1, pgam, flag, feat1);  // feat1 -> pa_feat

  // CAM
  k_cam_attn<<<512, 128, 0, stream>>>(feat2, attn);
  k_cam_out<<<4096, 256, 0, stream>>>(feat2, attn, cgam, flag, cafeat);

  // second convs
  k_conv<128,3,128,0,false><<<2048,256,0,stream>>>(feat1,  nullptr, w21r, scale + 256, shift + 256, nullptr, flag, vbuf,   nullptr); // pa_conv
  k_conv<128,3,128,0,false><<<2048,256,0,stream>>>(cafeat, nullptr, w22r, scale + 384, shift + 384, nullptr, flag, caconv, nullptr); // ca_conv

  // heads -> d_out [3][4][64][4096] (dtype per flag)
  const size_t SEC = (size_t)4 * 64 * HW;  // 1,048,576 elements per section
  u16*   outB = (u16*)d_out;
  float* outF = (float*)d_out;
  k_conv<128,1,64,3,false><<<1024,256,0,stream>>>(vbuf,   nullptr, w31b, nullptr, nullptr, b31, flag, outB,           outF);
  k_conv<128,1,64,3,false><<<1024,256,0,stream>>>(caconv, nullptr, w32b, nullptr, nullptr, b32, flag, outB + SEC,     outF + SEC);
  k_conv<128,1,64,3,true ><<<1024,256,0,stream>>>(vbuf,   caconv,  w4b,  nullptr, nullptr, b4,  flag, outB + 2 * SEC, outF + 2 * SEC);
}